// Round 3
// baseline (9167.902 us; speedup 1.0000x reference)
//
#include <hip/hip_runtime.h>
#include <math.h>

#define BB 4
#define TT 10
#define CIN 64
#define COUT 64
#define HH 96
#define WW 96
#define HWSZ (HH*WW)
#define LL 5

// ---------------- Kernel A: i2h 3x3 conv (pad 1), reshape remap q = t*B + b ----------------
// 32x8 tile, 16 co/thread, double-buffered LDS staging with register prefetch.
__global__ __launch_bounds__(256) void i2h_conv_kernel(const float* __restrict__ x,
                                                       const float* __restrict__ w,
                                                       const float* __restrict__ bias,
                                                       float* __restrict__ out, int t) {
    const int tile = blockIdx.x;               // 0..35
    const int tx0 = (tile % 3) * 32;
    const int ty0 = (tile / 3) * 8;
    const int co0 = blockIdx.y * 16;           // 12 groups -> 192
    const int b   = blockIdx.z;
    __shared__ float s[2][340];                // (8+2) x (32+2)
    const int tid = threadIdx.x;
    const int tx = tid & 31, ty = tid >> 5;

    int off0 = 0, off1 = 0; bool ok0 = false, ok1 = false;
    {
        int i = tid, r = i / 34, c = i % 34;
        int gy = ty0 + r - 1, gx = tx0 + c - 1;
        ok0 = (gy >= 0 && gy < HH && gx >= 0 && gx < WW);
        off0 = gy * WW + gx;
        i = tid + 256;
        if (i < 340) {
            r = i / 34; c = i % 34;
            gy = ty0 + r - 1; gx = tx0 + c - 1;
            ok1 = (gy >= 0 && gy < HH && gx >= 0 && gx < WW);
            off1 = gy * WW + gx;
        }
    }
    const bool has1 = (tid + 256) < 340;

    float acc[16];
    #pragma unroll
    for (int j = 0; j < 16; j++) acc[j] = bias[co0 + j];

    const float* src = x + (size_t)(t * BB + b) * CIN * HWSZ;

    s[0][tid] = ok0 ? src[off0] : 0.0f;
    if (has1) s[0][tid + 256] = ok1 ? src[off1] : 0.0f;

    for (int ci = 0; ci < CIN; ci++) {
        const int cur = ci & 1;
        float pf0 = 0.0f, pf1 = 0.0f;
        if (ci + 1 < CIN) {
            const float* sp = src + (size_t)(ci + 1) * HWSZ;
            pf0 = ok0 ? sp[off0] : 0.0f;
            if (has1) pf1 = ok1 ? sp[off1] : 0.0f;
        }
        __syncthreads();
        float tap[9];
        #pragma unroll
        for (int r = 0; r < 3; r++)
            #pragma unroll
            for (int c = 0; c < 3; c++)
                tap[r * 3 + c] = s[cur][(ty + r) * 34 + tx + c];
        #pragma unroll
        for (int j = 0; j < 16; j++) {
            const float* wp = w + ((size_t)(co0 + j) * CIN + ci) * 9;  // block-uniform -> s_load
            #pragma unroll
            for (int k = 0; k < 9; k++) acc[j] += tap[k] * wp[k];
        }
        if (ci + 1 < CIN) {
            s[1 - cur][tid] = pf0;
            if (has1) s[1 - cur][tid + 256] = pf1;
        }
    }
    const int p = (ty0 + ty) * WW + tx0 + tx;
    #pragma unroll
    for (int j = 0; j < 16; j++)
        out[((size_t)b * 192 + co0 + j) * HWSZ + p] = acc[j];
}

// ---------------- Kernel B: f1 partial = conv5x5(x_t,i2f) + conv5x5(h,h2f), ci-split x2 ----
// blockIdx.y = cg*2 + chalf; cg: co group of 8; chalf: ci half. No tanh here (fused in flows).
__global__ __launch_bounds__(256) void f1_kernel(const float* __restrict__ x,
                                                 const float* __restrict__ h,
                                                 const float* __restrict__ wi, const float* __restrict__ bi,
                                                 const float* __restrict__ wh, const float* __restrict__ bh,
                                                 float* __restrict__ f1p, int t) {
    const int tile = blockIdx.x;
    const int tx0 = (tile % 3) * 32;
    const int ty0 = (tile / 3) * 8;
    const int cg    = blockIdx.y >> 1;    // 0..3
    const int chalf = blockIdx.y & 1;     // 0..1
    const int co0 = cg * 8;
    const int cb  = chalf * 32;
    const int b   = blockIdx.z;
    __shared__ float sx[2][432];          // (8+4) x (32+4)
    __shared__ float sh[2][432];
    const int tid = threadIdx.x;
    const int tx = tid & 31, ty = tid >> 5;

    int off0 = 0, off1 = 0; bool ok0 = false, ok1 = false;
    {
        int i = tid, r = i / 36, c = i % 36;
        int gy = ty0 + r - 2, gx = tx0 + c - 2;
        ok0 = (gy >= 0 && gy < HH && gx >= 0 && gx < WW);
        off0 = gy * WW + gx;
        i = tid + 256;
        if (i < 432) {
            r = i / 36; c = i % 36;
            gy = ty0 + r - 2; gx = tx0 + c - 2;
            ok1 = (gy >= 0 && gy < HH && gx >= 0 && gx < WW);
            off1 = gy * WW + gx;
        }
    }
    const bool has1 = (tid + 256) < 432;

    float acc[8];
    #pragma unroll
    for (int j = 0; j < 8; j++) acc[j] = (chalf == 0) ? (bi[co0 + j] + bh[co0 + j]) : 0.0f;

    const float* xs = x + ((size_t)b * TT + t) * CIN * HWSZ + (size_t)cb * HWSZ;
    const float* hs = h + (size_t)b * CIN * HWSZ + (size_t)cb * HWSZ;

    sx[0][tid] = ok0 ? xs[off0] : 0.0f;
    sh[0][tid] = ok0 ? hs[off0] : 0.0f;
    if (has1) {
        sx[0][tid + 256] = ok1 ? xs[off1] : 0.0f;
        sh[0][tid + 256] = ok1 ? hs[off1] : 0.0f;
    }

    for (int ci = 0; ci < 32; ci++) {
        const int cur = ci & 1;
        float px0 = 0, ph0 = 0, px1 = 0, ph1 = 0;
        if (ci + 1 < 32) {
            const float* xp = xs + (size_t)(ci + 1) * HWSZ;
            const float* hp = hs + (size_t)(ci + 1) * HWSZ;
            px0 = ok0 ? xp[off0] : 0.0f; ph0 = ok0 ? hp[off0] : 0.0f;
            if (has1) { px1 = ok1 ? xp[off1] : 0.0f; ph1 = ok1 ? hp[off1] : 0.0f; }
        }
        __syncthreads();
        float tapx[25], taph[25];
        #pragma unroll
        for (int r = 0; r < 5; r++)
            #pragma unroll
            for (int c = 0; c < 5; c++) {
                tapx[r * 5 + c] = sx[cur][(ty + r) * 36 + tx + c];
                taph[r * 5 + c] = sh[cur][(ty + r) * 36 + tx + c];
            }
        const int cig = cb + ci;
        #pragma unroll
        for (int j = 0; j < 8; j++) {
            const float* wp = wi + ((size_t)(co0 + j) * CIN + cig) * 25;  // uniform
            const float* wq = wh + ((size_t)(co0 + j) * CIN + cig) * 25;  // uniform
            #pragma unroll
            for (int k = 0; k < 25; k++) acc[j] += tapx[k] * wp[k] + taph[k] * wq[k];
        }
        if (ci + 1 < 32) {
            sx[1 - cur][tid] = px0; sh[1 - cur][tid] = ph0;
            if (has1) { sx[1 - cur][tid + 256] = px1; sh[1 - cur][tid + 256] = ph1; }
        }
    }
    const int p = (ty0 + ty) * WW + tx0 + tx;
    #pragma unroll
    for (int j = 0; j < 8; j++)
        f1p[(((size_t)chalf * BB + b) * 32 + co0 + j) * HWSZ + p] = acc[j];
}

// ---------------- Kernel C: flows partial = conv5x5(tanh(f1pa+f1pb), w), ci-split x4 ------
__global__ __launch_bounds__(256) void flows_kernel(const float* __restrict__ f1p,
                                                    const float* __restrict__ w,
                                                    const float* __restrict__ bias,
                                                    float* __restrict__ flp) {
    const int tile = blockIdx.x;
    const int tx0 = (tile % 3) * 32;
    const int ty0 = (tile / 3) * 8;
    const int q = blockIdx.y;            // ci quarter: [q*8, q*8+8)
    const int b = blockIdx.z;
    __shared__ float s[2][432];
    const int tid = threadIdx.x;
    const int tx = tid & 31, ty = tid >> 5;

    int off0 = 0, off1 = 0; bool ok0 = false, ok1 = false;
    {
        int i = tid, r = i / 36, c = i % 36;
        int gy = ty0 + r - 2, gx = tx0 + c - 2;
        ok0 = (gy >= 0 && gy < HH && gx >= 0 && gx < WW);
        off0 = gy * WW + gx;
        i = tid + 256;
        if (i < 432) {
            r = i / 36; c = i % 36;
            gy = ty0 + r - 2; gx = tx0 + c - 2;
            ok1 = (gy >= 0 && gy < HH && gx >= 0 && gx < WW);
            off1 = gy * WW + gx;
        }
    }
    const bool has1 = (tid + 256) < 432;

    float acc[10];
    #pragma unroll
    for (int j = 0; j < 10; j++) acc[j] = (q == 0) ? bias[j] : 0.0f;

    const float* pa = f1p + ((size_t)b * 32 + q * 8) * HWSZ;            // chalf=0
    const float* pb = f1p + (((size_t)BB + b) * 32 + q * 8) * HWSZ;     // chalf=1

    s[0][tid] = ok0 ? tanhf(pa[off0] + pb[off0]) : 0.0f;
    if (has1) s[0][tid + 256] = ok1 ? tanhf(pa[off1] + pb[off1]) : 0.0f;

    for (int ci = 0; ci < 8; ci++) {
        const int cur = ci & 1;
        float pa0 = 0, pb0 = 0, pa1 = 0, pb1 = 0;
        if (ci + 1 < 8) {
            const float* ap = pa + (size_t)(ci + 1) * HWSZ;
            const float* bp = pb + (size_t)(ci + 1) * HWSZ;
            pa0 = ok0 ? ap[off0] : 0.0f; pb0 = ok0 ? bp[off0] : 0.0f;
            if (has1) { pa1 = ok1 ? ap[off1] : 0.0f; pb1 = ok1 ? bp[off1] : 0.0f; }
        }
        __syncthreads();
        float tap[25];
        #pragma unroll
        for (int r = 0; r < 5; r++)
            #pragma unroll
            for (int c = 0; c < 5; c++)
                tap[r * 5 + c] = s[cur][(ty + r) * 36 + tx + c];
        const int cig = q * 8 + ci;
        #pragma unroll
        for (int j = 0; j < 10; j++) {
            const float* wp = w + ((size_t)j * 32 + cig) * 25;  // uniform
            #pragma unroll
            for (int k = 0; k < 25; k++) acc[j] += tap[k] * wp[k];
        }
        if (ci + 1 < 8) {
            s[1 - cur][tid] = ok0 ? tanhf(pa0 + pb0) : 0.0f;
            if (has1) s[1 - cur][tid + 256] = ok1 ? tanhf(pa1 + pb1) : 0.0f;
        }
    }
    const int p = (ty0 + ty) * WW + tx0 + tx;
    #pragma unroll
    for (int j = 0; j < 10; j++)
        flp[(((size_t)q * BB + b) * 10 + j) * HWSZ + p] = acc[j];
}

// ---------------- Kernel D: bilinear warp of h by -flow (sum 4 flow partials) --------------
__global__ __launch_bounds__(256) void warp_kernel(const float* __restrict__ h,
                                                   const float* __restrict__ flp,
                                                   float* __restrict__ out) {
    const int p = blockIdx.x * 256 + threadIdx.x;  // plane index
    const int l = blockIdx.y;                      // 0..4
    const int b = blockIdx.z;
    const int y = p / WW, xx = p % WW;
    float a0 = 0.0f, a1 = 0.0f;
    #pragma unroll
    for (int q = 0; q < 4; q++) {
        a0 += flp[(((size_t)q * BB + b) * 10 + l * 2 + 0) * HWSZ + p];
        a1 += flp[(((size_t)q * BB + b) * 10 + l * 2 + 1) * HWSZ + p];
    }
    const float f0  = -a0;
    const float f1v = -a1;
    const float nx = 2.0f * ((float)xx + f0)  / (float)(WW - 1) - 1.0f;
    const float ny = 2.0f * ((float)y  + f1v) / (float)(HH - 1) - 1.0f;
    const float fx = (nx + 1.0f) * (WW * 0.5f) - 0.5f;
    const float fy = (ny + 1.0f) * (HH * 0.5f) - 0.5f;
    const float x0f = floorf(fx), y0f = floorf(fy);
    const float wx = fx - x0f, wy = fy - y0f;
    const int x0 = (int)x0f, y0 = (int)y0f;

    int   off[4];
    float wgt[4];
    #pragma unroll
    for (int k = 0; k < 4; k++) {
        const int yi = y0 + (k >> 1);
        const int xi = x0 + (k & 1);
        const bool ok = (xi >= 0 && xi < WW && yi >= 0 && yi < HH);
        const int yc = min(max(yi, 0), HH - 1);
        const int xc = min(max(xi, 0), WW - 1);
        off[k] = yc * WW + xc;
        const float wk = ((k & 1) ? wx : 1.0f - wx) * ((k >> 1) ? wy : 1.0f - wy);
        wgt[k] = ok ? wk : 0.0f;
    }
    const float* hp = h + (size_t)b * COUT * HWSZ;
    float* op = out + ((size_t)b * (LL * COUT) + l * COUT) * HWSZ + p;
    for (int c = 0; c < COUT; c++) {
        const float* hc = hp + (size_t)c * HWSZ;
        const float o = hc[off[0]] * wgt[0] + hc[off[1]] * wgt[1]
                      + hc[off[2]] * wgt[2] + hc[off[3]] * wgt[3];
        op[(size_t)c * HWSZ] = o;
    }
}

// ---------------- Kernel E: fused h2h (1x1, 320->192) + GRU gates + state update -----------
// blockIdx.y = c-group of 8; each thread computes r/u/m dot products for 8 channels.
__global__ __launch_bounds__(256) void h2h_gate_kernel(const float* __restrict__ warped,
                                                       const float* __restrict__ w,
                                                       const float* __restrict__ bias,
                                                       const float* __restrict__ i2h,
                                                       float* h, float* __restrict__ outs,
                                                       float* __restrict__ last_h, int t) {
    const int p  = blockIdx.x * 256 + threadIdx.x;
    const int c0 = blockIdx.y * 8;                 // 8 groups -> 64 channels
    const int b  = blockIdx.z;
    float ar[8], au[8], am[8];
    #pragma unroll
    for (int j = 0; j < 8; j++) {
        ar[j] = bias[c0 + j];
        au[j] = bias[64 + c0 + j];
        am[j] = bias[128 + c0 + j];
    }
    const float* wp0 = warped + (size_t)b * 320 * HWSZ + p;
    for (int k = 0; k < 320; k++) {
        const float v = wp0[(size_t)k * HWSZ];
        #pragma unroll
        for (int j = 0; j < 8; j++) {
            ar[j] += v * w[(size_t)(c0 + j) * 320 + k];         // uniform -> s_load
            au[j] += v * w[(size_t)(64 + c0 + j) * 320 + k];
            am[j] += v * w[(size_t)(128 + c0 + j) * 320 + k];
        }
    }
    const size_t ib = (size_t)b * 192 * HWSZ + p;
    #pragma unroll
    for (int j = 0; j < 8; j++) {
        const int c = c0 + j;
        const float i_r = i2h[ib + (size_t)c * HWSZ];
        const float i_u = i2h[ib + (size_t)(64 + c) * HWSZ];
        const float i_m = i2h[ib + (size_t)(128 + c) * HWSZ];
        const float r = 1.0f / (1.0f + expf(-(i_r + ar[j])));
        const float u = 1.0f / (1.0f + expf(-(i_u + au[j])));
        const float m = tanhf(i_m + r * am[j]);
        const size_t hidx = ((size_t)b * COUT + c) * HWSZ + p;
        const float nh = u * h[hidx] + (1.0f - u) * m;
        h[hidx] = nh;
        outs[(((size_t)b * TT + t) * COUT + c) * HWSZ + p] = nh;
        if (t == TT - 1) last_h[hidx] = nh;
    }
}

extern "C" void kernel_launch(void* const* d_in, const int* in_sizes, int n_in,
                              void* d_out, int out_size, void* d_ws, size_t ws_size,
                              hipStream_t stream) {
    const float* inputs  = (const float*)d_in[0];
    const float* i2h_w   = (const float*)d_in[1];
    const float* i2h_b   = (const float*)d_in[2];
    const float* i2f_w   = (const float*)d_in[3];
    const float* i2f_b   = (const float*)d_in[4];
    const float* h2f_w   = (const float*)d_in[5];
    const float* h2f_b   = (const float*)d_in[6];
    const float* flows_w = (const float*)d_in[7];
    const float* flows_b = (const float*)d_in[8];
    const float* ret_w   = (const float*)d_in[9];
    const float* ret_b   = (const float*)d_in[10];

    float* out = (float*)d_out;
    float* ws  = (float*)d_ws;

    // workspace layout (floats), total ~100.3 MB
    float* h      = ws;                       // 4*64*9216      = 2,359,296
    float* i2h_t  = h + 2359296;              // 4*192*9216     = 7,077,888
    float* f1p    = i2h_t + 7077888;          // 2*4*32*9216    = 2,359,296
    float* flp    = f1p + 2359296;            // 4*4*10*9216    = 1,474,560
    float* warped = flp + 1474560;            // 4*320*9216     = 11,796,480

    float* outs   = out;                      // (B,T,64,H,W)
    float* last_h = out + (size_t)BB * TT * COUT * HWSZ;

    hipMemsetAsync(h, 0, (size_t)BB * COUT * HWSZ * sizeof(float), stream);

    const int PBLK = HWSZ / 256;  // 36
    for (int t = 0; t < TT; t++) {
        i2h_conv_kernel<<<dim3(36, 12, BB), 256, 0, stream>>>(inputs, i2h_w, i2h_b, i2h_t, t);
        f1_kernel<<<dim3(36, 8, BB), 256, 0, stream>>>(inputs, h, i2f_w, i2f_b, h2f_w, h2f_b, f1p, t);
        flows_kernel<<<dim3(36, 4, BB), 256, 0, stream>>>(f1p, flows_w, flows_b, flp);
        warp_kernel<<<dim3(PBLK, LL, BB), 256, 0, stream>>>(h, flp, warped);
        h2h_gate_kernel<<<dim3(PBLK, 8, BB), 256, 0, stream>>>(warped, ret_w, ret_b, i2h_t, h, outs, last_h, t);
    }
}

// Round 4
// 3920.449 us; speedup vs baseline: 2.3385x; 2.3385x over previous
//
#include <hip/hip_runtime.h>
#include <math.h>

#define BB 4
#define TT 10
#define HH 96
#define WW 96
#define HWSZ 9216
#define LL 5

typedef _Float16 half8 __attribute__((ext_vector_type(8)));
typedef _Float16 half4 __attribute__((ext_vector_type(4)));
typedef float floatx4 __attribute__((ext_vector_type(4)));

// ---------------- prep: weights -> f16, MFMA-friendly [co][k] layouts ----------------
// wi16/wh16: [co=32][k=1600], k = tap*64 + ci   (tap = ky*5+kx)
// wA16:      [co=192][k=576], k = tap*64 + ci   (tap = ky*3+kx)
// rw16:      [co=192][k=320], k = l*64 + c
__global__ __launch_bounds__(256) void prep_weights(const float* __restrict__ i2f_w,
                                                    const float* __restrict__ h2f_w,
                                                    const float* __restrict__ i2h_w,
                                                    const float* __restrict__ ret_w,
                                                    _Float16* __restrict__ wi16,
                                                    _Float16* __restrict__ wh16,
                                                    _Float16* __restrict__ wA16,
                                                    _Float16* __restrict__ rw16) {
    const int id = blockIdx.x * 256 + threadIdx.x;   // 0..274431
    if (id < 51200) {
        const int co = id / 1600, k = id % 1600, tap = k >> 6, ci = k & 63;
        wi16[id] = (_Float16)i2f_w[(co * 64 + ci) * 25 + tap];
    } else if (id < 102400) {
        const int r = id - 51200;
        const int co = r / 1600, k = r % 1600, tap = k >> 6, ci = k & 63;
        wh16[r] = (_Float16)h2f_w[(co * 64 + ci) * 25 + tap];
    } else if (id < 212992) {
        const int r = id - 102400;
        const int co = r / 576, k = r % 576, tap = k >> 6, ci = k & 63;
        wA16[r] = (_Float16)i2h_w[(co * 64 + ci) * 9 + tap];
    } else {
        const int r = id - 212992;
        rw16[r] = (_Float16)ret_w[r];   // already [co][320] with k = l*64+c
    }
}

// ---------------- prep: x -> f16 channel-last x16[img][pos][ci], img = b*10+t (flat) ----
__global__ __launch_bounds__(256) void prep_x16(const float* __restrict__ x,
                                                _Float16* __restrict__ x16) {
    const int id = blockIdx.x * 256 + threadIdx.x;   // 0..368639
    const int img = id / HWSZ, pos = id % HWSZ;
    const float* src = x + (size_t)img * 64 * HWSZ + pos;
    _Float16* dst = x16 + ((size_t)img * HWSZ + pos) * 64;
    #pragma unroll
    for (int i = 0; i < 8; i++) {
        half8 v;
        #pragma unroll
        for (int j = 0; j < 8; j++)
            v[j] = (_Float16)src[(size_t)(i * 8 + j) * HWSZ];
        *(half8*)(dst + i * 8) = v;
    }
}

// ---------------- i2h: 3x3 conv as MFMA implicit GEMM (M=192, K=576, N=16/wave) -------
// image remap: step t, batch b reads flat image q = t*4 + b
__global__ __launch_bounds__(256) void i2h_mfma(const _Float16* __restrict__ x16,
                                                const _Float16* __restrict__ wA16,
                                                const float* __restrict__ bias,
                                                float* __restrict__ out, int t) {
    const int wv = threadIdx.x >> 6;
    const int ln = threadIdx.x & 63;
    const int lm = ln & 15, q = ln >> 4;
    const int nt = blockIdx.x * 4 + wv;          // 0..2303
    const int b  = nt / 576;
    const int ti = nt % 576;
    const int y  = ti / 6;
    const int x0 = (ti % 6) * 16;
    const _Float16* xb = x16 + (size_t)(t * BB + b) * HWSZ * 64;

    floatx4 acc[12];
    #pragma unroll
    for (int mt = 0; mt < 12; mt++)
        #pragma unroll
        for (int r = 0; r < 4; r++)
            acc[mt][r] = bias[mt * 16 + q * 4 + r];

    for (int s = 0; s < 18; s++) {
        const int tap = s >> 1;
        const int ky = tap / 3 - 1, kx = tap % 3 - 1;
        const int ci0 = (s & 1) * 32;
        const int k0 = tap * 64 + ci0;
        const int gy = y + ky, gx = x0 + lm + kx;
        half8 bf = {};
        if (gy >= 0 && gy < HH && gx >= 0 && gx < WW)
            bf = *(const half8*)(xb + (size_t)(gy * WW + gx) * 64 + ci0 + q * 8);
        #pragma unroll
        for (int mt = 0; mt < 12; mt++) {
            const half8 af = *(const half8*)(wA16 + (size_t)(mt * 16 + lm) * 576 + k0 + q * 8);
            acc[mt] = __builtin_amdgcn_mfma_f32_16x16x32_f16(af, bf, acc[mt], 0, 0, 0);
        }
    }
    const int pos = y * WW + x0 + lm;
    #pragma unroll
    for (int mt = 0; mt < 12; mt++)
        #pragma unroll
        for (int r = 0; r < 4; r++)
            out[((size_t)b * 192 + mt * 16 + q * 4 + r) * HWSZ + pos] = acc[mt][r];
}

// ---------------- f1: tanh(conv5x5(x_t)+conv5x5(h)) as MFMA (M=32, K=2x1600) ----------
__global__ __launch_bounds__(256) void f1_mfma(const _Float16* __restrict__ x16,
                                               const _Float16* __restrict__ h16,
                                               const _Float16* __restrict__ wi16,
                                               const _Float16* __restrict__ wh16,
                                               const float* __restrict__ bi,
                                               const float* __restrict__ bh,
                                               float* __restrict__ out, int t) {
    const int wv = threadIdx.x >> 6;
    const int ln = threadIdx.x & 63;
    const int lm = ln & 15, q = ln >> 4;
    const int nt0 = (blockIdx.x * 4 + wv) * 2;   // two n-tiles, same b (576 even)
    const int b   = nt0 / 576;
    const int ti0 = nt0 % 576;
    const int y0 = ti0 / 6, xx0 = (ti0 % 6) * 16;
    const int y1 = (ti0 + 1) / 6, xx1 = ((ti0 + 1) % 6) * 16;

    floatx4 acc[2][2];
    #pragma unroll
    for (int mt = 0; mt < 2; mt++)
        #pragma unroll
        for (int r = 0; r < 4; r++) {
            const float bv = bi[mt * 16 + q * 4 + r] + bh[mt * 16 + q * 4 + r];
            acc[mt][0][r] = bv;
            acc[mt][1][r] = bv;
        }

    const _Float16* src0 = x16 + (size_t)(b * TT + t) * HWSZ * 64;  // x_t = inputs[:, t]
    const _Float16* src1 = h16 + (size_t)b * HWSZ * 64;

    for (int phase = 0; phase < 2; phase++) {
        const _Float16* src = phase ? src1 : src0;
        const _Float16* wt  = phase ? wh16 : wi16;
        for (int s = 0; s < 50; s++) {
            const int tap = s >> 1;
            const int ky = tap / 5 - 2, kx = tap % 5 - 2;
            const int ci0 = (s & 1) * 32;
            const int k0 = tap * 64 + ci0;
            half8 b0 = {}, b1 = {};
            {
                const int gy = y0 + ky, gx = xx0 + lm + kx;
                if (gy >= 0 && gy < HH && gx >= 0 && gx < WW)
                    b0 = *(const half8*)(src + (size_t)(gy * WW + gx) * 64 + ci0 + q * 8);
            }
            {
                const int gy = y1 + ky, gx = xx1 + lm + kx;
                if (gy >= 0 && gy < HH && gx >= 0 && gx < WW)
                    b1 = *(const half8*)(src + (size_t)(gy * WW + gx) * 64 + ci0 + q * 8);
            }
            const half8 a0 = *(const half8*)(wt + (size_t)(0 * 16 + lm) * 1600 + k0 + q * 8);
            const half8 a1 = *(const half8*)(wt + (size_t)(1 * 16 + lm) * 1600 + k0 + q * 8);
            acc[0][0] = __builtin_amdgcn_mfma_f32_16x16x32_f16(a0, b0, acc[0][0], 0, 0, 0);
            acc[0][1] = __builtin_amdgcn_mfma_f32_16x16x32_f16(a0, b1, acc[0][1], 0, 0, 0);
            acc[1][0] = __builtin_amdgcn_mfma_f32_16x16x32_f16(a1, b0, acc[1][0], 0, 0, 0);
            acc[1][1] = __builtin_amdgcn_mfma_f32_16x16x32_f16(a1, b1, acc[1][1], 0, 0, 0);
        }
    }
    const int pos0 = y0 * WW + xx0 + lm;
    const int pos1 = y1 * WW + xx1 + lm;
    #pragma unroll
    for (int mt = 0; mt < 2; mt++)
        #pragma unroll
        for (int r = 0; r < 4; r++) {
            const int co = mt * 16 + q * 4 + r;
            out[((size_t)b * 32 + co) * HWSZ + pos0] = tanhf(acc[mt][0][r]);
            out[((size_t)b * 32 + co) * HWSZ + pos1] = tanhf(acc[mt][1][r]);
        }
}

// ---------------- flows: conv5x5(f1, flows_w) + b  (fp32, round-2 tiled version) ------
__global__ __launch_bounds__(256) void flows_kernel(const float* __restrict__ f1,
                                                    const float* __restrict__ w,
                                                    const float* __restrict__ bias,
                                                    float* __restrict__ out) {
    const int tile = blockIdx.x;
    const int tx0 = (tile % 3) * 32;
    const int ty0 = (tile / 3) * 8;
    const int b   = blockIdx.z;
    __shared__ float s[12 * 36];
    const int tid = threadIdx.x;
    const int tx = tid & 31, ty = tid >> 5;

    float acc[10];
    #pragma unroll
    for (int j = 0; j < 10; j++) acc[j] = bias[j];

    const float* src = f1 + (size_t)b * 32 * HWSZ;
    for (int ci = 0; ci < 32; ci++) {
        __syncthreads();
        for (int i = tid; i < 432; i += 256) {
            const int r = i / 36, c = i % 36;
            const int gy = ty0 + r - 2, gx = tx0 + c - 2;
            const bool ok = (gy >= 0 && gy < HH && gx >= 0 && gx < WW);
            s[i] = ok ? src[(size_t)ci * HWSZ + gy * WW + gx] : 0.0f;
        }
        __syncthreads();
        float tap[25];
        #pragma unroll
        for (int r = 0; r < 5; r++)
            #pragma unroll
            for (int c = 0; c < 5; c++)
                tap[r * 5 + c] = s[(ty + r) * 36 + tx + c];
        #pragma unroll
        for (int j = 0; j < 10; j++) {
            const float* wp = w + ((size_t)j * 32 + ci) * 25;  // uniform
            #pragma unroll
            for (int k = 0; k < 25; k++) acc[j] += tap[k] * wp[k];
        }
    }
    const int p = (ty0 + ty) * WW + tx0 + tx;
    #pragma unroll
    for (int j = 0; j < 10; j++)
        out[((size_t)b * 10 + j) * HWSZ + p] = acc[j];
}

// ---------------- warp: bilinear warp of h by -flow, writes f16 channel-last ----------
// warped16[b][pos][l*64+c]
__global__ __launch_bounds__(256) void warp_kernel(const float* __restrict__ h,
                                                   const float* __restrict__ flows,
                                                   _Float16* __restrict__ w16) {
    const int p = blockIdx.x * 256 + threadIdx.x;
    const int l = blockIdx.y;
    const int b = blockIdx.z;
    const int y = p / WW, xx = p % WW;
    const float f0  = -flows[((size_t)b * 10 + l * 2 + 0) * HWSZ + p];
    const float f1v = -flows[((size_t)b * 10 + l * 2 + 1) * HWSZ + p];
    const float nx = 2.0f * ((float)xx + f0)  / (float)(WW - 1) - 1.0f;
    const float ny = 2.0f * ((float)y  + f1v) / (float)(HH - 1) - 1.0f;
    const float fx = (nx + 1.0f) * (WW * 0.5f) - 0.5f;
    const float fy = (ny + 1.0f) * (HH * 0.5f) - 0.5f;
    const float x0f = floorf(fx), y0f = floorf(fy);
    const float wx = fx - x0f, wy = fy - y0f;
    const int x0 = (int)x0f, y0 = (int)y0f;

    int   off[4];
    float wgt[4];
    #pragma unroll
    for (int k = 0; k < 4; k++) {
        const int yi = y0 + (k >> 1);
        const int xi = x0 + (k & 1);
        const bool ok = (xi >= 0 && xi < WW && yi >= 0 && yi < HH);
        const int yc = min(max(yi, 0), HH - 1);
        const int xc = min(max(xi, 0), WW - 1);
        off[k] = yc * WW + xc;
        const float wk = ((k & 1) ? wx : 1.0f - wx) * ((k >> 1) ? wy : 1.0f - wy);
        wgt[k] = ok ? wk : 0.0f;
    }
    const float* hp = h + (size_t)b * 64 * HWSZ;
    _Float16* dst = w16 + ((size_t)b * HWSZ + p) * 320 + l * 64;
    #pragma unroll
    for (int i = 0; i < 8; i++) {
        half8 v;
        #pragma unroll
        for (int j = 0; j < 8; j++) {
            const float* hc = hp + (size_t)(i * 8 + j) * HWSZ;
            v[j] = (_Float16)(hc[off[0]] * wgt[0] + hc[off[1]] * wgt[1]
                            + hc[off[2]] * wgt[2] + hc[off[3]] * wgt[3]);
        }
        *(half8*)(dst + i * 8) = v;
    }
}

// ---------------- h2h (1x1, 320->192) as MFMA + fused GRU gates -----------------------
// r/u/m rows land in m-tiles mt, mt+4, mt+8 at identical lane/reg -> direct gate fusion.
__global__ __launch_bounds__(256) void gate_mfma(const _Float16* __restrict__ w16,
                                                 const _Float16* __restrict__ rw16,
                                                 const float* __restrict__ ret_b,
                                                 const float* __restrict__ i2h,
                                                 float* __restrict__ h,
                                                 _Float16* __restrict__ h16,
                                                 float* __restrict__ outs,
                                                 float* __restrict__ last_h, int t) {
    const int wv = threadIdx.x >> 6;
    const int ln = threadIdx.x & 63;
    const int lm = ln & 15, q = ln >> 4;
    const int nt = blockIdx.x * 4 + wv;          // 0..2303
    const int b  = nt / 576;
    const int ti = nt % 576;
    const int pos = ti * 16 + lm;

    floatx4 acc[12];
    #pragma unroll
    for (int mt = 0; mt < 12; mt++)
        #pragma unroll
        for (int r = 0; r < 4; r++)
            acc[mt][r] = ret_b[mt * 16 + q * 4 + r];

    const _Float16* wb = w16 + ((size_t)b * HWSZ + pos) * 320;
    for (int s = 0; s < 10; s++) {
        const int k0 = s * 32;
        const half8 bf = *(const half8*)(wb + k0 + q * 8);
        #pragma unroll
        for (int mt = 0; mt < 12; mt++) {
            const half8 af = *(const half8*)(rw16 + (size_t)(mt * 16 + lm) * 320 + k0 + q * 8);
            acc[mt] = __builtin_amdgcn_mfma_f32_16x16x32_f16(af, bf, acc[mt], 0, 0, 0);
        }
    }

    const size_t ib = (size_t)b * 192 * HWSZ + pos;
    #pragma unroll
    for (int mt = 0; mt < 4; mt++) {
        half4 pk;
        #pragma unroll
        for (int r = 0; r < 4; r++) {
            const int c = mt * 16 + q * 4 + r;
            const float i_r = i2h[ib + (size_t)c * HWSZ];
            const float i_u = i2h[ib + (size_t)(64 + c) * HWSZ];
            const float i_m = i2h[ib + (size_t)(128 + c) * HWSZ];
            const float gr = acc[mt][r], gu = acc[mt + 4][r], gm = acc[mt + 8][r];
            const float rg = 1.0f / (1.0f + expf(-(i_r + gr)));
            const float ug = 1.0f / (1.0f + expf(-(i_u + gu)));
            const float mg = tanhf(i_m + rg * gm);
            const size_t hi = ((size_t)b * 64 + c) * HWSZ + pos;
            const float nh = ug * h[hi] + (1.0f - ug) * mg;
            h[hi] = nh;
            outs[(((size_t)b * TT + t) * 64 + c) * HWSZ + pos] = nh;
            if (t == TT - 1) last_h[hi] = nh;
            pk[r] = (_Float16)nh;
        }
        *(half4*)(h16 + ((size_t)b * HWSZ + pos) * 64 + mt * 16 + q * 4) = pk;
    }
}

extern "C" void kernel_launch(void* const* d_in, const int* in_sizes, int n_in,
                              void* d_out, int out_size, void* d_ws, size_t ws_size,
                              hipStream_t stream) {
    const float* inputs  = (const float*)d_in[0];
    const float* i2h_w   = (const float*)d_in[1];
    const float* i2h_b   = (const float*)d_in[2];
    const float* i2f_w   = (const float*)d_in[3];
    const float* i2f_b   = (const float*)d_in[4];
    const float* h2f_w   = (const float*)d_in[5];
    const float* h2f_b   = (const float*)d_in[6];
    const float* flows_w = (const float*)d_in[7];
    const float* flows_b = (const float*)d_in[8];
    const float* ret_w   = (const float*)d_in[9];
    const float* ret_b   = (const float*)d_in[10];

    float* out = (float*)d_out;

    // workspace layout (bytes), total ~115.3 MB (< round-1's proven 117.8 MB)
    char* base = (char*)d_ws;
    float* h       = (float*)base;            base += 9437184;    // 4*64*9216 f32
    float* i2h_t   = (float*)base;            base += 28311552;   // 4*192*9216 f32
    float* flowsb  = (float*)base;            base += 1474560;    // 4*10*9216 f32
    char* shared   = base;                    base += 23592960;   // union region
    _Float16* warped16 = (_Float16*)shared;                       // 4*9216*320 f16
    float*    f1p      = (float*)shared;                          // 4*32*9216 f32 (disjoint lifetime)
    _Float16* x16  = (_Float16*)base;         base += 47185920;   // 40*9216*64 f16
    _Float16* h16  = (_Float16*)base;         base += 4718592;    // 4*9216*64 f16
    _Float16* wi16 = (_Float16*)base;         base += 102400;     // 32*1600 f16
    _Float16* wh16 = (_Float16*)base;         base += 102400;
    _Float16* wA16 = (_Float16*)base;         base += 221184;     // 192*576 f16
    _Float16* rw16 = (_Float16*)base;         base += 122880;     // 192*320 f16

    float* outs   = out;
    float* last_h = out + (size_t)BB * TT * 64 * HWSZ;

    hipMemsetAsync(h,   0, 9437184, stream);
    hipMemsetAsync(h16, 0, 4718592, stream);

    prep_weights<<<1072, 256, 0, stream>>>(i2f_w, h2f_w, i2h_w, ret_w, wi16, wh16, wA16, rw16);
    prep_x16<<<1440, 256, 0, stream>>>(inputs, x16);

    for (int t = 0; t < TT; t++) {
        i2h_mfma<<<576, 256, 0, stream>>>(x16, wA16, i2h_b, i2h_t, t);
        f1_mfma<<<288, 256, 0, stream>>>(x16, h16, wi16, wh16, i2f_b, h2f_b, f1p, t);
        flows_kernel<<<dim3(36, 1, BB), 256, 0, stream>>>(f1p, flows_w, flows_b, flowsb);
        warp_kernel<<<dim3(36, LL, BB), 256, 0, stream>>>(h, flowsb, warped16);
        gate_mfma<<<576, 256, 0, stream>>>(warped16, rw16, ret_b, i2h_t, h, h16, outs, last_h, t);
    }
}

// Round 5
// 3027.888 us; speedup vs baseline: 3.0278x; 1.2948x over previous
//
#include <hip/hip_runtime.h>
#include <math.h>

#define BB 4
#define TT 10
#define HH 96
#define WW 96
#define HWSZ 9216
#define LL 5

typedef _Float16 half8 __attribute__((ext_vector_type(8)));
typedef _Float16 half4 __attribute__((ext_vector_type(4)));
typedef float floatx4 __attribute__((ext_vector_type(4)));

// ---------------- prep: weights -> f16, MFMA-friendly [co][k] layouts ----------------
// wi16/wh16: [co=32][k=1600], k = tap*64 + ci   (tap = ky*5+kx)
// wA16:      [co=192][k=576], k = tap*64 + ci   (tap = ky*3+kx)
// rw16:      [co=192][k=320], k = l*64 + c
// fw16:      [co=16(10 live)][k=800], k = tap*32 + ci
__global__ __launch_bounds__(256) void prep_weights(const float* __restrict__ i2f_w,
                                                    const float* __restrict__ h2f_w,
                                                    const float* __restrict__ i2h_w,
                                                    const float* __restrict__ ret_w,
                                                    const float* __restrict__ flows_w,
                                                    _Float16* __restrict__ wi16,
                                                    _Float16* __restrict__ wh16,
                                                    _Float16* __restrict__ wA16,
                                                    _Float16* __restrict__ rw16,
                                                    _Float16* __restrict__ fw16) {
    const int id = blockIdx.x * 256 + threadIdx.x;   // 0..287231
    if (id < 51200) {
        const int co = id / 1600, k = id % 1600, tap = k >> 6, ci = k & 63;
        wi16[id] = (_Float16)i2f_w[(co * 64 + ci) * 25 + tap];
    } else if (id < 102400) {
        const int r = id - 51200;
        const int co = r / 1600, k = r % 1600, tap = k >> 6, ci = k & 63;
        wh16[r] = (_Float16)h2f_w[(co * 64 + ci) * 25 + tap];
    } else if (id < 212992) {
        const int r = id - 102400;
        const int co = r / 576, k = r % 576, tap = k >> 6, ci = k & 63;
        wA16[r] = (_Float16)i2h_w[(co * 64 + ci) * 9 + tap];
    } else if (id < 274432) {
        const int r = id - 212992;
        rw16[r] = (_Float16)ret_w[r];   // already [co][320] with k = l*64+c
    } else {
        const int r = id - 274432;      // 0..12799
        const int co = r / 800, k = r % 800, tap = k >> 5, ci = k & 31;
        fw16[r] = (co < 10) ? (_Float16)flows_w[(co * 32 + ci) * 25 + tap] : (_Float16)0.0f;
    }
}

// ---------------- prep: x -> f16 channel-last x16[img][pos][ci], img flat ----
__global__ __launch_bounds__(256) void prep_x16(const float* __restrict__ x,
                                                _Float16* __restrict__ x16) {
    const int id = blockIdx.x * 256 + threadIdx.x;   // 0..368639
    const int img = id / HWSZ, pos = id % HWSZ;
    const float* src = x + (size_t)img * 64 * HWSZ + pos;
    _Float16* dst = x16 + ((size_t)img * HWSZ + pos) * 64;
    #pragma unroll
    for (int i = 0; i < 8; i++) {
        half8 v;
        #pragma unroll
        for (int j = 0; j < 8; j++)
            v[j] = (_Float16)src[(size_t)(i * 8 + j) * HWSZ];
        *(half8*)(dst + i * 8) = v;
    }
}

// ---------------- i2h: 3x3 conv as MFMA implicit GEMM, output f16 channel-last -------
// image remap: step t, batch b reads flat image q = t*4 + b
__global__ __launch_bounds__(256) void i2h_mfma(const _Float16* __restrict__ x16,
                                                const _Float16* __restrict__ wA16,
                                                const float* __restrict__ bias,
                                                _Float16* __restrict__ i2h16, int t) {
    const int wv = threadIdx.x >> 6;
    const int ln = threadIdx.x & 63;
    const int lm = ln & 15, q = ln >> 4;
    const int nt = blockIdx.x * 4 + wv;          // 0..2303
    const int b  = nt / 576;
    const int ti = nt % 576;
    const int y  = ti / 6;
    const int x0 = (ti % 6) * 16;
    const _Float16* xb = x16 + (size_t)(t * BB + b) * HWSZ * 64;

    floatx4 acc[12];
    #pragma unroll
    for (int mt = 0; mt < 12; mt++)
        #pragma unroll
        for (int r = 0; r < 4; r++)
            acc[mt][r] = bias[mt * 16 + q * 4 + r];

    for (int s = 0; s < 18; s++) {
        const int tap = s >> 1;
        const int ky = tap / 3 - 1, kx = tap % 3 - 1;
        const int ci0 = (s & 1) * 32;
        const int k0 = tap * 64 + ci0;
        const int gy = y + ky, gx = x0 + lm + kx;
        half8 bf = {};
        if (gy >= 0 && gy < HH && gx >= 0 && gx < WW)
            bf = *(const half8*)(xb + (size_t)(gy * WW + gx) * 64 + ci0 + q * 8);
        #pragma unroll
        for (int mt = 0; mt < 12; mt++) {
            const half8 af = *(const half8*)(wA16 + (size_t)(mt * 16 + lm) * 576 + k0 + q * 8);
            acc[mt] = __builtin_amdgcn_mfma_f32_16x16x32_f16(af, bf, acc[mt], 0, 0, 0);
        }
    }
    const int pos = y * WW + x0 + lm;
    _Float16* op = i2h16 + ((size_t)b * HWSZ + pos) * 192;
    #pragma unroll
    for (int mt = 0; mt < 12; mt++) {
        half4 pk;
        #pragma unroll
        for (int r = 0; r < 4; r++) pk[r] = (_Float16)acc[mt][r];
        *(half4*)(op + mt * 16 + q * 4) = pk;
    }
}

// ---------------- f1: tanh(conv5x5(x_t)+conv5x5(h)), 1 n-tile/wave, f16 out ----------
__global__ __launch_bounds__(256) void f1_mfma(const _Float16* __restrict__ x16,
                                               const _Float16* __restrict__ h16,
                                               const _Float16* __restrict__ wi16,
                                               const _Float16* __restrict__ wh16,
                                               const float* __restrict__ bi,
                                               const float* __restrict__ bh,
                                               _Float16* __restrict__ f116, int t) {
    const int wv = threadIdx.x >> 6;
    const int ln = threadIdx.x & 63;
    const int lm = ln & 15, q = ln >> 4;
    const int nt = blockIdx.x * 4 + wv;          // 0..2303
    const int b  = nt / 576;
    const int ti = nt % 576;
    const int y  = ti / 6, xx = (ti % 6) * 16;

    floatx4 acc[2];
    #pragma unroll
    for (int mt = 0; mt < 2; mt++)
        #pragma unroll
        for (int r = 0; r < 4; r++)
            acc[mt][r] = bi[mt * 16 + q * 4 + r] + bh[mt * 16 + q * 4 + r];

    const _Float16* src0 = x16 + (size_t)(b * TT + t) * HWSZ * 64;  // x_t = inputs[:, t]
    const _Float16* src1 = h16 + (size_t)b * HWSZ * 64;

    for (int phase = 0; phase < 2; phase++) {
        const _Float16* src = phase ? src1 : src0;
        const _Float16* wt  = phase ? wh16 : wi16;
        for (int s = 0; s < 50; s++) {
            const int tap = s >> 1;
            const int ky = tap / 5 - 2, kx = tap % 5 - 2;
            const int ci0 = (s & 1) * 32;
            const int k0 = tap * 64 + ci0;
            const int gy = y + ky, gx = xx + lm + kx;
            half8 bf = {};
            if (gy >= 0 && gy < HH && gx >= 0 && gx < WW)
                bf = *(const half8*)(src + (size_t)(gy * WW + gx) * 64 + ci0 + q * 8);
            const half8 a0 = *(const half8*)(wt + (size_t)(0 * 16 + lm) * 1600 + k0 + q * 8);
            const half8 a1 = *(const half8*)(wt + (size_t)(1 * 16 + lm) * 1600 + k0 + q * 8);
            acc[0] = __builtin_amdgcn_mfma_f32_16x16x32_f16(a0, bf, acc[0], 0, 0, 0);
            acc[1] = __builtin_amdgcn_mfma_f32_16x16x32_f16(a1, bf, acc[1], 0, 0, 0);
        }
    }
    const int pos = y * WW + xx + lm;
    _Float16* op = f116 + ((size_t)b * HWSZ + pos) * 32;
    #pragma unroll
    for (int mt = 0; mt < 2; mt++) {
        half4 pk;
        #pragma unroll
        for (int r = 0; r < 4; r++) pk[r] = (_Float16)tanhf(acc[mt][r]);
        *(half4*)(op + mt * 16 + q * 4) = pk;
    }
}

// ---------------- flows: conv5x5(f1,32->10) as MFMA (M=16, 10 live; K=800) -----------
__global__ __launch_bounds__(256) void flows_mfma(const _Float16* __restrict__ f116,
                                                  const _Float16* __restrict__ fw16,
                                                  const float* __restrict__ bias,
                                                  float* __restrict__ out) {
    const int wv = threadIdx.x >> 6;
    const int ln = threadIdx.x & 63;
    const int lm = ln & 15, q = ln >> 4;
    const int nt = blockIdx.x * 4 + wv;          // 0..2303
    const int b  = nt / 576;
    const int ti = nt % 576;
    const int y  = ti / 6, xx = (ti % 6) * 16;

    floatx4 acc;
    #pragma unroll
    for (int r = 0; r < 4; r++) {
        const int c = q * 4 + r;
        acc[r] = (c < 10) ? bias[c] : 0.0f;
    }
    const _Float16* fb = f116 + (size_t)b * HWSZ * 32;
    #pragma unroll 5
    for (int tap = 0; tap < 25; tap++) {
        const int ky = tap / 5 - 2, kx = tap % 5 - 2;
        const int gy = y + ky, gx = xx + lm + kx;
        half8 bf = {};
        if (gy >= 0 && gy < HH && gx >= 0 && gx < WW)
            bf = *(const half8*)(fb + (size_t)(gy * WW + gx) * 32 + q * 8);
        const half8 af = *(const half8*)(fw16 + (size_t)lm * 800 + tap * 32 + q * 8);
        acc = __builtin_amdgcn_mfma_f32_16x16x32_f16(af, bf, acc, 0, 0, 0);
    }
    const int pos = y * WW + xx + lm;
    #pragma unroll
    for (int r = 0; r < 4; r++) {
        const int c = q * 4 + r;
        if (c < 10)
            out[((size_t)b * 10 + c) * HWSZ + pos] = acc[r];
    }
}

// ---------------- warp: bilinear warp of h16 by -flow, writes f16 channel-last --------
__global__ __launch_bounds__(256) void warp_kernel(const _Float16* __restrict__ h16,
                                                   const float* __restrict__ flows,
                                                   _Float16* __restrict__ w16) {
    const int p = blockIdx.x * 256 + threadIdx.x;
    const int l = blockIdx.y;
    const int b = blockIdx.z;
    const int y = p / WW, xx = p % WW;
    const float f0  = -flows[((size_t)b * 10 + l * 2 + 0) * HWSZ + p];
    const float f1v = -flows[((size_t)b * 10 + l * 2 + 1) * HWSZ + p];
    const float nx = 2.0f * ((float)xx + f0)  / (float)(WW - 1) - 1.0f;
    const float ny = 2.0f * ((float)y  + f1v) / (float)(HH - 1) - 1.0f;
    const float fx = (nx + 1.0f) * (WW * 0.5f) - 0.5f;
    const float fy = (ny + 1.0f) * (HH * 0.5f) - 0.5f;
    const float x0f = floorf(fx), y0f = floorf(fy);
    const float wx = fx - x0f, wy = fy - y0f;
    const int x0 = (int)x0f, y0 = (int)y0f;

    int   off[4];
    float wgt[4];
    #pragma unroll
    for (int k = 0; k < 4; k++) {
        const int yi = y0 + (k >> 1);
        const int xi = x0 + (k & 1);
        const bool ok = (xi >= 0 && xi < WW && yi >= 0 && yi < HH);
        const int yc = min(max(yi, 0), HH - 1);
        const int xc = min(max(xi, 0), WW - 1);
        off[k] = yc * WW + xc;
        const float wk = ((k & 1) ? wx : 1.0f - wx) * ((k >> 1) ? wy : 1.0f - wy);
        wgt[k] = ok ? wk : 0.0f;
    }
    const _Float16* hb = h16 + (size_t)b * HWSZ * 64;
    _Float16* dst = w16 + ((size_t)b * HWSZ + p) * 320 + l * 64;
    #pragma unroll
    for (int i = 0; i < 8; i++) {
        const half8 v0 = *(const half8*)(hb + (size_t)off[0] * 64 + i * 8);
        const half8 v1 = *(const half8*)(hb + (size_t)off[1] * 64 + i * 8);
        const half8 v2 = *(const half8*)(hb + (size_t)off[2] * 64 + i * 8);
        const half8 v3 = *(const half8*)(hb + (size_t)off[3] * 64 + i * 8);
        half8 o;
        #pragma unroll
        for (int j = 0; j < 8; j++)
            o[j] = (_Float16)((float)v0[j] * wgt[0] + (float)v1[j] * wgt[1]
                            + (float)v2[j] * wgt[2] + (float)v3[j] * wgt[3]);
        *(half8*)(dst + i * 8) = o;
    }
}

// ---------------- h2h (1x1, 320->192) as MFMA + fused GRU gates -----------------------
__global__ __launch_bounds__(256) void gate_mfma(const _Float16* __restrict__ w16,
                                                 const _Float16* __restrict__ rw16,
                                                 const float* __restrict__ ret_b,
                                                 const _Float16* __restrict__ i2h16,
                                                 float* __restrict__ h,
                                                 _Float16* __restrict__ h16,
                                                 float* __restrict__ outs,
                                                 float* __restrict__ last_h, int t) {
    const int wv = threadIdx.x >> 6;
    const int ln = threadIdx.x & 63;
    const int lm = ln & 15, q = ln >> 4;
    const int nt = blockIdx.x * 4 + wv;          // 0..2303
    const int b  = nt / 576;
    const int ti = nt % 576;
    const int pos = ti * 16 + lm;

    floatx4 acc[12];
    #pragma unroll
    for (int mt = 0; mt < 12; mt++)
        #pragma unroll
        for (int r = 0; r < 4; r++)
            acc[mt][r] = ret_b[mt * 16 + q * 4 + r];

    const _Float16* wb = w16 + ((size_t)b * HWSZ + pos) * 320;
    for (int s = 0; s < 10; s++) {
        const int k0 = s * 32;
        const half8 bf = *(const half8*)(wb + k0 + q * 8);
        #pragma unroll
        for (int mt = 0; mt < 12; mt++) {
            const half8 af = *(const half8*)(rw16 + (size_t)(mt * 16 + lm) * 320 + k0 + q * 8);
            acc[mt] = __builtin_amdgcn_mfma_f32_16x16x32_f16(af, bf, acc[mt], 0, 0, 0);
        }
    }

    const _Float16* ip = i2h16 + ((size_t)b * HWSZ + pos) * 192;
    #pragma unroll
    for (int mt = 0; mt < 4; mt++) {
        const half4 vr = *(const half4*)(ip + mt * 16 + q * 4);
        const half4 vu = *(const half4*)(ip + 64 + mt * 16 + q * 4);
        const half4 vm = *(const half4*)(ip + 128 + mt * 16 + q * 4);
        half4 pk;
        #pragma unroll
        for (int r = 0; r < 4; r++) {
            const int c = mt * 16 + q * 4 + r;
            const float gr = acc[mt][r], gu = acc[mt + 4][r], gm = acc[mt + 8][r];
            const float rg = 1.0f / (1.0f + expf(-((float)vr[r] + gr)));
            const float ug = 1.0f / (1.0f + expf(-((float)vu[r] + gu)));
            const float mg = tanhf((float)vm[r] + rg * gm);
            const size_t hi = ((size_t)b * 64 + c) * HWSZ + pos;
            const float nh = ug * h[hi] + (1.0f - ug) * mg;
            h[hi] = nh;
            outs[(((size_t)b * TT + t) * 64 + c) * HWSZ + pos] = nh;
            if (t == TT - 1) last_h[hi] = nh;
            pk[r] = (_Float16)nh;
        }
        *(half4*)(h16 + ((size_t)b * HWSZ + pos) * 64 + mt * 16 + q * 4) = pk;
    }
}

extern "C" void kernel_launch(void* const* d_in, const int* in_sizes, int n_in,
                              void* d_out, int out_size, void* d_ws, size_t ws_size,
                              hipStream_t stream) {
    const float* inputs  = (const float*)d_in[0];
    const float* i2h_w   = (const float*)d_in[1];
    const float* i2h_b   = (const float*)d_in[2];
    const float* i2f_w   = (const float*)d_in[3];
    const float* i2f_b   = (const float*)d_in[4];
    const float* h2f_w   = (const float*)d_in[5];
    const float* h2f_b   = (const float*)d_in[6];
    const float* flows_w = (const float*)d_in[7];
    const float* flows_b = (const float*)d_in[8];
    const float* ret_w   = (const float*)d_in[9];
    const float* ret_b   = (const float*)d_in[10];

    float* out = (float*)d_out;

    // workspace layout (bytes), total ~103.5 MB
    char* base = (char*)d_ws;
    float*    h        = (float*)base;      base += 9437184;    // 4*64*9216 f32
    _Float16* i2h16    = (_Float16*)base;   base += 14155776;   // 4*9216*192 f16
    float*    flowsb   = (float*)base;      base += 1474560;    // 4*10*9216 f32
    _Float16* warped16 = (_Float16*)base;   base += 23592960;   // 4*9216*320 f16
    _Float16* f116     = (_Float16*)base;   base += 2359296;    // 4*9216*32 f16
    _Float16* x16      = (_Float16*)base;   base += 47185920;   // 40*9216*64 f16
    _Float16* h16      = (_Float16*)base;   base += 4718592;    // 4*9216*64 f16
    _Float16* wi16     = (_Float16*)base;   base += 102400;     // 32*1600
    _Float16* wh16     = (_Float16*)base;   base += 102400;
    _Float16* wA16     = (_Float16*)base;   base += 221184;     // 192*576
    _Float16* rw16     = (_Float16*)base;   base += 122880;     // 192*320
    _Float16* fw16     = (_Float16*)base;   base += 25600;      // 16*800

    float* outs   = out;
    float* last_h = out + (size_t)BB * TT * 64 * HWSZ;

    hipMemsetAsync(h,   0, 9437184, stream);
    hipMemsetAsync(h16, 0, 4718592, stream);

    prep_weights<<<1122, 256, 0, stream>>>(i2f_w, h2f_w, i2h_w, ret_w, flows_w,
                                           wi16, wh16, wA16, rw16, fw16);
    prep_x16<<<1440, 256, 0, stream>>>(inputs, x16);

    for (int t = 0; t < TT; t++) {
        i2h_mfma<<<576, 256, 0, stream>>>(x16, wA16, i2h_b, i2h16, t);
        f1_mfma<<<576, 256, 0, stream>>>(x16, h16, wi16, wh16, i2f_b, h2f_b, f116, t);
        flows_mfma<<<576, 256, 0, stream>>>(f116, fw16, flows_b, flowsb);
        warp_kernel<<<dim3(36, LL, BB), 256, 0, stream>>>(h16, flowsb, warped16);
        gate_mfma<<<576, 256, 0, stream>>>(warped16, rw16, ret_b, i2h16, h, h16, outs, last_h, t);
    }
}